// Round 1
// baseline (1008.188 us; speedup 1.0000x reference)
//
#include <hip/hip_runtime.h>
#include <stdint.h>

#define T_TOK 4096
#define DIMD  1024
#define HIDN  2048
#define NEXP  8
#define RMAX  9216   // 8192 slots + 8*128 max alignment padding

typedef float f32x4 __attribute__((ext_vector_type(4)));
typedef short s16x8 __attribute__((ext_vector_type(8)));

__device__ __forceinline__ uint16_t f2bf(float f) {
    uint32_t u = __builtin_bit_cast(uint32_t, f);
    u += 0x7fffu + ((u >> 16) & 1u);
    return (uint16_t)(u >> 16);
}
__device__ __forceinline__ float bf2f(uint32_t h) {
    return __builtin_bit_cast(float, h << 16);
}
__device__ __forceinline__ uint32_t pk2(float a, float b) {
    return (uint32_t)f2bf(a) | ((uint32_t)f2bf(b) << 16);
}
// swizzled LDS byte offset: 128B row pitch, XOR row bits into 16B-granule slot
__device__ __forceinline__ int swz(int r, int cbyte) {
    return r * 128 + (cbyte ^ ((r & 7) << 4));
}

// ---------------- small kernels ----------------

__global__ void cvt_x_kernel(const float* __restrict__ x, uint16_t* __restrict__ xb) {
    int i = blockIdx.x * blockDim.x + threadIdx.x;
    float4 v = ((const float4*)x)[i];
    uint2 o; o.x = pk2(v.x, v.y); o.y = pk2(v.z, v.w);
    ((uint2*)xb)[i] = o;
}

__global__ void router_kernel(const float* __restrict__ x, const float* __restrict__ rw,
                              const float* __restrict__ bias,
                              int* __restrict__ sel, float* __restrict__ wgt) {
    int t = blockIdx.x;
    int lane = threadIdx.x;            // 64 threads = 1 wave
    int e = lane & 7, seg = lane >> 3; // 8 lanes per expert, 8 segments of 128
    const float* xr = x + (size_t)t * DIMD + seg * 128;
    const float* wr = rw + (size_t)e * DIMD + seg * 128;
    float s = 0.f;
    #pragma unroll 8
    for (int i = 0; i < 128; ++i) s += xr[i] * wr[i];
    s += __shfl_xor(s, 8, 64);
    s += __shfl_xor(s, 16, 64);
    s += __shfl_xor(s, 32, 64);
    __shared__ float lg[8];
    if (lane < 8) lg[lane] = s + bias[lane];
    __syncthreads();
    if (lane == 0) {
        float l0 = -1e30f; int i0 = 0;
        #pragma unroll
        for (int i = 0; i < 8; ++i) { float v = lg[i]; if (v > l0) { l0 = v; i0 = i; } }
        float l1 = -1e30f; int i1 = 0;
        #pragma unroll
        for (int i = 0; i < 8; ++i) { if (i == i0) continue; float v = lg[i]; if (v > l1) { l1 = v; i1 = i; } }
        float e1 = expf(l1 - l0);      // l0 >= l1 -> e1 <= 1
        float d = 1.f + e1;
        sel[t * 2] = i0; sel[t * 2 + 1] = i1;
        wgt[t * 2] = 1.f / d; wgt[t * 2 + 1] = e1 / d;
    }
}

__global__ void count_kernel(const int* __restrict__ sel, int* __restrict__ cnt) {
    int i = blockIdx.x * blockDim.x + threadIdx.x;
    if (i < T_TOK * 2) atomicAdd(&cnt[sel[i]], 1);
}

__global__ void offs_kernel(const int* __restrict__ cnt, int* __restrict__ offs) {
    if (threadIdx.x == 0 && blockIdx.x == 0) {
        int o = 0;
        for (int e = 0; e < NEXP; ++e) { offs[e] = o; o += (cnt[e] + 127) & ~127; }
        offs[NEXP] = o;
    }
}

__global__ void assign_kernel(const int* __restrict__ sel, const int* __restrict__ offs,
                              int* __restrict__ fill, int* __restrict__ row_of) {
    int i = blockIdx.x * blockDim.x + threadIdx.x;
    if (i < T_TOK * 2) {
        int e = sel[i];
        row_of[i] = offs[e] + atomicAdd(&fill[e], 1);
    }
}

__global__ void gather_kernel(const uint16_t* __restrict__ xb, const int* __restrict__ row_of,
                              uint16_t* __restrict__ Xg) {
    int slot = blockIdx.x;
    int pos = row_of[slot];
    int t = slot >> 1;
    const uint4* src = (const uint4*)(xb + (size_t)t * DIMD);
    uint4* dst = (uint4*)(Xg + (size_t)pos * DIMD);
    dst[threadIdx.x] = src[threadIdx.x];   // 128 thr * 16B = 2048B row
}

__global__ void combine_kernel(const uint16_t* __restrict__ H2g, const int* __restrict__ row_of,
                               const float* __restrict__ wgt, float* __restrict__ out) {
    int t = blockIdx.x;
    int c = threadIdx.x * 8;   // 128 threads * 8 cols
    int r0 = row_of[t * 2], r1 = row_of[t * 2 + 1];
    float w0 = wgt[t * 2], w1 = wgt[t * 2 + 1];
    uint4 a = *(const uint4*)(H2g + (size_t)r0 * DIMD + c);
    uint4 b = *(const uint4*)(H2g + (size_t)r1 * DIMD + c);
    float* o = out + (size_t)t * DIMD + c;
    o[0] += w0 * bf2f(a.x & 0xffffu) + w1 * bf2f(b.x & 0xffffu);
    o[1] += w0 * bf2f(a.x >> 16)     + w1 * bf2f(b.x >> 16);
    o[2] += w0 * bf2f(a.y & 0xffffu) + w1 * bf2f(b.y & 0xffffu);
    o[3] += w0 * bf2f(a.y >> 16)     + w1 * bf2f(b.y >> 16);
    o[4] += w0 * bf2f(a.z & 0xffffu) + w1 * bf2f(b.z & 0xffffu);
    o[5] += w0 * bf2f(a.z >> 16)     + w1 * bf2f(b.z >> 16);
    o[6] += w0 * bf2f(a.w & 0xffffu) + w1 * bf2f(b.w & 0xffffu);
    o[7] += w0 * bf2f(a.w >> 16)     + w1 * bf2f(b.w >> 16);
}

// ---------------- GEMM kernels ----------------
// 128x128 tile, BK=64, 4 waves in 2x2, each wave 64x64 via 4x4 frags of 16x16x32 MFMA.
// A is bf16 [*, K]; B is f32 [N, K] converted to bf16 during reg-staged LDS write.

template<int ROUTED>
__global__ __launch_bounds__(256, 2)
void gemm13_kernel(const uint16_t* __restrict__ A,
                   const float* __restrict__ W1, const float* __restrict__ W3,
                   uint16_t* __restrict__ H, int ldh,
                   const int* __restrict__ offs) {
    __shared__ __align__(16) char lds[49152];
    char* As  = lds;
    char* B1s = lds + 16384;
    char* B3s = lds + 32768;

    const int K = DIMD;
    int row0 = blockIdx.x * 128;
    const float *b1 = W1, *b3 = W3;
    if (ROUTED) {
        if (row0 >= offs[NEXP]) return;
        int e = 0;
        while (row0 >= offs[e + 1]) ++e;
        size_t eo = (size_t)e * HIDN * DIMD;
        b1 += eo; b3 += eo;
    }
    int col0 = blockIdx.y * 128;

    int tid = threadIdx.x, lane = tid & 63;
    int wv = tid >> 6, wm = wv >> 1, wn = wv & 1;

    f32x4 acc1[4][4] = {};
    f32x4 acc3[4][4] = {};

    int srow = tid >> 3;
    int skk  = (tid & 7) * 8;   // element offset in k within tile

    for (int kt = 0; kt < K; kt += 64) {
        __syncthreads();
        #pragma unroll
        for (int it = 0; it < 4; ++it) {
            int r = it * 32 + srow;
            uint4 v = *(const uint4*)(A + (size_t)(row0 + r) * K + kt + skk);
            *(uint4*)(As + swz(r, skk * 2)) = v;
        }
        #pragma unroll
        for (int it = 0; it < 4; ++it) {
            int r = it * 32 + srow;
            const float* p1 = b1 + (size_t)(col0 + r) * K + kt + skk;
            float4 u0 = *(const float4*)p1;
            float4 u1 = *(const float4*)(p1 + 4);
            uint4 w;
            w.x = pk2(u0.x, u0.y); w.y = pk2(u0.z, u0.w);
            w.z = pk2(u1.x, u1.y); w.w = pk2(u1.z, u1.w);
            *(uint4*)(B1s + swz(r, skk * 2)) = w;
            const float* p3 = b3 + (size_t)(col0 + r) * K + kt + skk;
            float4 t0 = *(const float4*)p3;
            float4 t1 = *(const float4*)(p3 + 4);
            uint4 w3v;
            w3v.x = pk2(t0.x, t0.y); w3v.y = pk2(t0.z, t0.w);
            w3v.z = pk2(t1.x, t1.y); w3v.w = pk2(t1.z, t1.w);
            *(uint4*)(B3s + swz(r, skk * 2)) = w3v;
        }
        __syncthreads();

        #pragma unroll
        for (int s = 0; s < 2; ++s) {
            int cb = s * 64 + ((lane >> 4) << 4);
            s16x8 av[4];
            #pragma unroll
            for (int i = 0; i < 4; ++i)
                av[i] = *(const s16x8*)(As + swz(wm * 64 + i * 16 + (lane & 15), cb));
            #pragma unroll
            for (int j = 0; j < 4; ++j) {
                int br = wn * 64 + j * 16 + (lane & 15);
                s16x8 bv1 = *(const s16x8*)(B1s + swz(br, cb));
                s16x8 bv3 = *(const s16x8*)(B3s + swz(br, cb));
                #pragma unroll
                for (int i = 0; i < 4; ++i) {
                    acc1[i][j] = __builtin_amdgcn_mfma_f32_16x16x32_bf16(av[i], bv1, acc1[i][j], 0, 0, 0);
                    acc3[i][j] = __builtin_amdgcn_mfma_f32_16x16x32_bf16(av[i], bv3, acc3[i][j], 0, 0, 0);
                }
            }
        }
    }

    #pragma unroll
    for (int i = 0; i < 4; ++i) {
        #pragma unroll
        for (int j = 0; j < 4; ++j) {
            #pragma unroll
            for (int rg = 0; rg < 4; ++rg) {
                int row = row0 + wm * 64 + i * 16 + ((lane >> 4) << 2) + rg;
                int col = col0 + wn * 64 + j * 16 + (lane & 15);
                float a1 = acc1[i][j][rg];
                float a3 = acc3[i][j][rg];
                float hv = (a1 / (1.f + __expf(-a1))) * a3;   // silu(a1)*a3
                H[(size_t)row * ldh + col] = f2bf(hv);
            }
        }
    }
}

// GEMM2: C[M,1024] = A[M,K] (bf16) * B^T, B rows indexed with per-kSplit expert stride.
// ROUTED=1: expert from offs, bf16 store to H2g. ROUTED=0: f32 accumulate into out.
template<int ROUTED>
__global__ __launch_bounds__(256, 2)
void gemm2_kernel(const uint16_t* __restrict__ A, int lda,
                  const float* __restrict__ W2, void* __restrict__ Cout,
                  const int* __restrict__ offs,
                  int K, int kSplit, long long expStride) {
    __shared__ __align__(16) char lds[32768];
    char* As = lds;
    char* Bs = lds + 16384;

    int row0 = blockIdx.x * 128;
    const float* b2 = W2;
    if (ROUTED) {
        if (row0 >= offs[NEXP]) return;
        int e = 0;
        while (row0 >= offs[e + 1]) ++e;
        b2 += (size_t)e * DIMD * HIDN;
    }
    int col0 = blockIdx.y * 128;

    int tid = threadIdx.x, lane = tid & 63;
    int wv = tid >> 6, wm = wv >> 1, wn = wv & 1;

    f32x4 acc[4][4] = {};
    int srow = tid >> 3;
    int skk  = (tid & 7) * 8;

    for (int kt = 0; kt < K; kt += 64) {
        const float* bb = b2 + (size_t)(kt / kSplit) * expStride + (kt % kSplit);
        __syncthreads();
        #pragma unroll
        for (int it = 0; it < 4; ++it) {
            int r = it * 32 + srow;
            uint4 v = *(const uint4*)(A + (size_t)(row0 + r) * lda + kt + skk);
            *(uint4*)(As + swz(r, skk * 2)) = v;
        }
        #pragma unroll
        for (int it = 0; it < 4; ++it) {
            int r = it * 32 + srow;
            const float* p = bb + (size_t)(col0 + r) * kSplit + skk;
            float4 u0 = *(const float4*)p;
            float4 u1 = *(const float4*)(p + 4);
            uint4 w;
            w.x = pk2(u0.x, u0.y); w.y = pk2(u0.z, u0.w);
            w.z = pk2(u1.x, u1.y); w.w = pk2(u1.z, u1.w);
            *(uint4*)(Bs + swz(r, skk * 2)) = w;
        }
        __syncthreads();

        #pragma unroll
        for (int s = 0; s < 2; ++s) {
            int cb = s * 64 + ((lane >> 4) << 4);
            s16x8 av[4];
            #pragma unroll
            for (int i = 0; i < 4; ++i)
                av[i] = *(const s16x8*)(As + swz(wm * 64 + i * 16 + (lane & 15), cb));
            #pragma unroll
            for (int j = 0; j < 4; ++j) {
                s16x8 bv = *(const s16x8*)(Bs + swz(wn * 64 + j * 16 + (lane & 15), cb));
                #pragma unroll
                for (int i = 0; i < 4; ++i)
                    acc[i][j] = __builtin_amdgcn_mfma_f32_16x16x32_bf16(av[i], bv, acc[i][j], 0, 0, 0);
            }
        }
    }

    #pragma unroll
    for (int i = 0; i < 4; ++i) {
        #pragma unroll
        for (int j = 0; j < 4; ++j) {
            #pragma unroll
            for (int rg = 0; rg < 4; ++rg) {
                int row = row0 + wm * 64 + i * 16 + ((lane >> 4) << 2) + rg;
                int col = col0 + wn * 64 + j * 16 + (lane & 15);
                float v = acc[i][j][rg];
                if (ROUTED) ((uint16_t*)Cout)[(size_t)row * DIMD + col] = f2bf(v);
                else        ((float*)Cout)[(size_t)row * DIMD + col] += v;
            }
        }
    }
}

// ---------------- launch ----------------

extern "C" void kernel_launch(void* const* d_in, const int* in_sizes, int n_in,
                              void* d_out, int out_size, void* d_ws, size_t ws_size,
                              hipStream_t stream) {
    const float* x   = (const float*)d_in[0];
    const float* rw  = (const float*)d_in[1];
    const float* eb  = (const float*)d_in[2];
    const float* w1  = (const float*)d_in[3];
    const float* w3  = (const float*)d_in[4];
    const float* w2  = (const float*)d_in[5];
    const float* sw1 = (const float*)d_in[6];
    const float* sw3 = (const float*)d_in[7];
    const float* sw2 = (const float*)d_in[8];
    float* out = (float*)d_out;

    char* ws = (char*)d_ws;
    size_t off = 0;
    auto alloc = [&](size_t b) { char* p = ws + off; off = (off + b + 255) & ~(size_t)255; return p; };
    uint16_t* xb  = (uint16_t*)alloc((size_t)T_TOK * DIMD * 2);   // x in bf16
    uint16_t* Xg  = (uint16_t*)alloc((size_t)RMAX * DIMD * 2);    // gathered tokens
    uint16_t* Hg  = (uint16_t*)alloc((size_t)RMAX * HIDN * 2);    // hidden (reused for shared, ldh=4096)
    uint16_t* H2g = (uint16_t*)alloc((size_t)RMAX * DIMD * 2);    // routed expert outputs
    int*   sel    = (int*)  alloc(T_TOK * 2 * 4);
    float* wgt    = (float*)alloc(T_TOK * 2 * 4);
    int*   row_of = (int*)  alloc(T_TOK * 2 * 4);
    int*   cnt    = (int*)  alloc(64);
    int*   fill   = (int*)  alloc(64);
    int*   offs   = (int*)  alloc(64);

    hipMemsetAsync(cnt, 0, 64, stream);
    hipMemsetAsync(fill, 0, 64, stream);
    hipMemsetAsync(Xg, 0, (size_t)RMAX * DIMD * 2, stream);      // zero pad rows
    hipMemsetAsync(out, 0, (size_t)out_size * sizeof(float), stream);

    cvt_x_kernel<<<4096, 256, 0, stream>>>(x, xb);
    router_kernel<<<T_TOK, 64, 0, stream>>>(x, rw, eb, sel, wgt);
    count_kernel<<<32, 256, 0, stream>>>(sel, cnt);
    offs_kernel<<<1, 1, 0, stream>>>(cnt, offs);
    assign_kernel<<<32, 256, 0, stream>>>(sel, offs, fill, row_of);
    gather_kernel<<<T_TOK * 2, 128, 0, stream>>>(xb, row_of, Xg);

    // routed experts: h = silu(Xg w1^T) * (Xg w3^T); H2g = h w2^T
    gemm13_kernel<1><<<dim3(RMAX / 128, HIDN / 128), 256, 0, stream>>>(Xg, w1, w3, Hg, HIDN, offs);
    gemm2_kernel<1><<<dim3(RMAX / 128, DIMD / 128), 256, 0, stream>>>(Hg, HIDN, w2, (void*)H2g, offs,
                                                                      HIDN, HIDN, 0);
    combine_kernel<<<T_TOK, 128, 0, stream>>>(H2g, row_of, wgt, out);

    // shared experts folded into one GEMM pair: N-concat for GEMM1, K-concat for GEMM2
    gemm13_kernel<0><<<dim3(T_TOK / 128, (2 * HIDN) / 128), 256, 0, stream>>>(xb, sw1, sw3, Hg, 2 * HIDN, nullptr);
    gemm2_kernel<0><<<dim3(T_TOK / 128, DIMD / 128), 256, 0, stream>>>(Hg, 2 * HIDN, sw2, (void*)out, nullptr,
                                                                       2 * HIDN, HIDN, (long long)DIMD * HIDN);
}

// Round 2
// 503.419 us; speedup vs baseline: 2.0027x; 2.0027x over previous
//
#include <hip/hip_runtime.h>
#include <stdint.h>

#define T_TOK 4096
#define DIMD  1024
#define HIDN  2048
#define NEXP  8
#define RMAX  9216   // 8192 slots + 8*128 max alignment padding

typedef float f32x4 __attribute__((ext_vector_type(4)));
typedef short s16x8 __attribute__((ext_vector_type(8)));

__device__ __forceinline__ uint16_t f2bf(float f) {
    uint32_t u = __builtin_bit_cast(uint32_t, f);
    u += 0x7fffu + ((u >> 16) & 1u);
    return (uint16_t)(u >> 16);
}
__device__ __forceinline__ float bf2f(uint32_t h) {
    return __builtin_bit_cast(float, h << 16);
}
__device__ __forceinline__ uint32_t pk2(float a, float b) {
    return (uint32_t)f2bf(a) | ((uint32_t)f2bf(b) << 16);
}
// swizzled LDS byte offset: 128B row pitch, XOR row bits into 16B-granule slot
__device__ __forceinline__ int swz(int r, int cbyte) {
    return r * 128 + (cbyte ^ ((r & 7) << 4));
}
// async global->LDS, 16B per lane, LDS dest = base + lane*16 (wave-uniform base)
__device__ __forceinline__ void gload16(const void* g, void* l) {
    __builtin_amdgcn_global_load_lds(
        (const __attribute__((address_space(1))) void*)g,
        (__attribute__((address_space(3))) void*)l, 16, 0, 0);
}
// Stage a 128x64 bf16 tile (16KB) into LDS with st-16 swizzle.
// LDS dest is linear (slot s at byte 16*s); global source is inverse-swizzled
// so that a swz(r,cb) read returns element (r, cb). 4 issues per lane.
__device__ __forceinline__ void stage128x64(const uint16_t* gbase, int ldk,
                                            char* lds, int wv, int lane) {
    #pragma unroll
    for (int i = 0; i < 4; ++i) {
        int s = (wv * 4 + i) * 64 + lane;
        int row = s >> 3;
        int cb = ((s & 7) << 4) ^ ((row & 7) << 4);
        gload16(gbase + (size_t)row * ldk + (cb >> 1), lds + ((wv * 4 + i) << 10));
    }
}

// ---------------- small kernels ----------------

__global__ void cvt_x_kernel(const float* __restrict__ x, uint16_t* __restrict__ xb) {
    int i = blockIdx.x * blockDim.x + threadIdx.x;
    float4 v = ((const float4*)x)[i];
    uint2 o; o.x = pk2(v.x, v.y); o.y = pk2(v.z, v.w);
    ((uint2*)xb)[i] = o;
}

__global__ void cvt_w_kernel(const float* __restrict__ s, uint16_t* __restrict__ d, int nquads) {
    int i = blockIdx.x * blockDim.x + threadIdx.x;
    int stride = gridDim.x * blockDim.x;
    for (; i < nquads; i += stride) {
        float4 v = ((const float4*)s)[i];
        uint2 o; o.x = pk2(v.x, v.y); o.y = pk2(v.z, v.w);
        ((uint2*)d)[i] = o;
    }
}

__global__ void router_kernel(const float* __restrict__ x, const float* __restrict__ rw,
                              const float* __restrict__ bias,
                              int* __restrict__ sel, float* __restrict__ wgt) {
    int t = blockIdx.x;
    int lane = threadIdx.x;            // 64 threads = 1 wave
    int e = lane & 7, seg = lane >> 3; // 8 lanes per expert, 8 segments of 128
    const float* xr = x + (size_t)t * DIMD + seg * 128;
    const float* wr = rw + (size_t)e * DIMD + seg * 128;
    float s = 0.f;
    #pragma unroll 8
    for (int i = 0; i < 128; ++i) s += xr[i] * wr[i];
    s += __shfl_xor(s, 8, 64);
    s += __shfl_xor(s, 16, 64);
    s += __shfl_xor(s, 32, 64);
    __shared__ float lg[8];
    if (lane < 8) lg[lane] = s + bias[lane];
    __syncthreads();
    if (lane == 0) {
        float l0 = -1e30f; int i0 = 0;
        #pragma unroll
        for (int i = 0; i < 8; ++i) { float v = lg[i]; if (v > l0) { l0 = v; i0 = i; } }
        float l1 = -1e30f; int i1 = 0;
        #pragma unroll
        for (int i = 0; i < 8; ++i) { if (i == i0) continue; float v = lg[i]; if (v > l1) { l1 = v; i1 = i; } }
        float e1 = expf(l1 - l0);      // l0 >= l1 -> e1 <= 1
        float d = 1.f + e1;
        sel[t * 2] = i0; sel[t * 2 + 1] = i1;
        wgt[t * 2] = 1.f / d; wgt[t * 2 + 1] = e1 / d;
    }
}

__global__ void count_kernel(const int* __restrict__ sel, int* __restrict__ cnt) {
    int i = blockIdx.x * blockDim.x + threadIdx.x;
    if (i < T_TOK * 2) atomicAdd(&cnt[sel[i]], 1);
}

__global__ void offs_kernel(const int* __restrict__ cnt, int* __restrict__ offs) {
    if (threadIdx.x == 0 && blockIdx.x == 0) {
        int o = 0;
        for (int e = 0; e < NEXP; ++e) { offs[e] = o; o += (cnt[e] + 127) & ~127; }
        offs[NEXP] = o;
    }
}

__global__ void assign_kernel(const int* __restrict__ sel, const int* __restrict__ offs,
                              int* __restrict__ fill, int* __restrict__ row_of) {
    int i = blockIdx.x * blockDim.x + threadIdx.x;
    if (i < T_TOK * 2) {
        int e = sel[i];
        row_of[i] = offs[e] + atomicAdd(&fill[e], 1);
    }
}

__global__ void gather_kernel(const uint16_t* __restrict__ xb, const int* __restrict__ row_of,
                              uint16_t* __restrict__ Xg) {
    int slot = blockIdx.x;
    int pos = row_of[slot];
    int t = slot >> 1;
    const uint4* src = (const uint4*)(xb + (size_t)t * DIMD);
    uint4* dst = (uint4*)(Xg + (size_t)pos * DIMD);
    dst[threadIdx.x] = src[threadIdx.x];   // 128 thr * 16B = 2048B row
}

__global__ void combine_kernel(const uint16_t* __restrict__ H2g, const int* __restrict__ row_of,
                               const float* __restrict__ wgt, float* __restrict__ out) {
    int t = blockIdx.x;
    int c = threadIdx.x * 8;   // 128 threads * 8 cols
    int r0 = row_of[t * 2], r1 = row_of[t * 2 + 1];
    float w0 = wgt[t * 2], w1 = wgt[t * 2 + 1];
    uint4 a = *(const uint4*)(H2g + (size_t)r0 * DIMD + c);
    uint4 b = *(const uint4*)(H2g + (size_t)r1 * DIMD + c);
    float* o = out + (size_t)t * DIMD + c;
    o[0] += w0 * bf2f(a.x & 0xffffu) + w1 * bf2f(b.x & 0xffffu);
    o[1] += w0 * bf2f(a.x >> 16)     + w1 * bf2f(b.x >> 16);
    o[2] += w0 * bf2f(a.y & 0xffffu) + w1 * bf2f(b.y & 0xffffu);
    o[3] += w0 * bf2f(a.y >> 16)     + w1 * bf2f(b.y >> 16);
    o[4] += w0 * bf2f(a.z & 0xffffu) + w1 * bf2f(b.z & 0xffffu);
    o[5] += w0 * bf2f(a.z >> 16)     + w1 * bf2f(b.z >> 16);
    o[6] += w0 * bf2f(a.w & 0xffffu) + w1 * bf2f(b.w & 0xffffu);
    o[7] += w0 * bf2f(a.w >> 16)     + w1 * bf2f(b.w >> 16);
}

// ---------------- GEMM kernels ----------------
// 128x128 tile, BK=64, 4 waves in 2x2, each wave 64x64 via 4x4 frags of 16x16x32 MFMA.
// All operands bf16; staging via global_load_lds (linear LDS dest, inverse-swizzled src).

template<int ROUTED>
__global__ __launch_bounds__(256, 2)
void gemm13_kernel(const uint16_t* __restrict__ A,
                   const uint16_t* __restrict__ W1, const uint16_t* __restrict__ W3,
                   uint16_t* __restrict__ H, int ldh,
                   const int* __restrict__ offs) {
    __shared__ __align__(16) char lds[49152];
    char* As  = lds;
    char* B1s = lds + 16384;
    char* B3s = lds + 32768;

    const int K = DIMD;
    int row0 = blockIdx.x * 128;
    const uint16_t *b1 = W1, *b3 = W3;
    if (ROUTED) {
        if (row0 >= offs[NEXP]) return;
        int e = 0;
        while (row0 >= offs[e + 1]) ++e;
        size_t eo = (size_t)e * HIDN * DIMD;
        b1 += eo; b3 += eo;
    }
    int col0 = blockIdx.y * 128;

    int tid = threadIdx.x, lane = tid & 63;
    int wv = tid >> 6, wm = wv >> 1, wn = wv & 1;

    f32x4 acc1[4][4] = {};
    f32x4 acc3[4][4] = {};

    for (int kt = 0; kt < K; kt += 64) {
        __syncthreads();
        stage128x64(A  + (size_t)row0 * K + kt, K, As,  wv, lane);
        stage128x64(b1 + (size_t)col0 * K + kt, K, B1s, wv, lane);
        stage128x64(b3 + (size_t)col0 * K + kt, K, B3s, wv, lane);
        __syncthreads();   // compiler drains vmcnt before s_barrier

        #pragma unroll
        for (int s = 0; s < 2; ++s) {
            int cb = s * 64 + ((lane >> 4) << 4);
            s16x8 av[4];
            #pragma unroll
            for (int i = 0; i < 4; ++i)
                av[i] = *(const s16x8*)(As + swz(wm * 64 + i * 16 + (lane & 15), cb));
            #pragma unroll
            for (int j = 0; j < 4; ++j) {
                int br = wn * 64 + j * 16 + (lane & 15);
                s16x8 bv1 = *(const s16x8*)(B1s + swz(br, cb));
                s16x8 bv3 = *(const s16x8*)(B3s + swz(br, cb));
                #pragma unroll
                for (int i = 0; i < 4; ++i) {
                    acc1[i][j] = __builtin_amdgcn_mfma_f32_16x16x32_bf16(av[i], bv1, acc1[i][j], 0, 0, 0);
                    acc3[i][j] = __builtin_amdgcn_mfma_f32_16x16x32_bf16(av[i], bv3, acc3[i][j], 0, 0, 0);
                }
            }
        }
    }

    #pragma unroll
    for (int i = 0; i < 4; ++i) {
        #pragma unroll
        for (int j = 0; j < 4; ++j) {
            #pragma unroll
            for (int rg = 0; rg < 4; ++rg) {
                int row = row0 + wm * 64 + i * 16 + ((lane >> 4) << 2) + rg;
                int col = col0 + wn * 64 + j * 16 + (lane & 15);
                float a1 = acc1[i][j][rg];
                float a3 = acc3[i][j][rg];
                float hv = (a1 / (1.f + __expf(-a1))) * a3;   // silu(a1)*a3
                H[(size_t)row * ldh + col] = f2bf(hv);
            }
        }
    }
}

// GEMM2: C[M,1024] = A[M,K] (bf16) * B^T (bf16), B rows indexed with per-kSplit expert stride.
// ROUTED=1: expert from offs, bf16 store to H2g. ROUTED=0: f32 accumulate into out.
template<int ROUTED>
__global__ __launch_bounds__(256, 3)
void gemm2_kernel(const uint16_t* __restrict__ A, int lda,
                  const uint16_t* __restrict__ W2, void* __restrict__ Cout,
                  const int* __restrict__ offs,
                  int K, int kSplit, long long expStride) {
    __shared__ __align__(16) char lds[32768];
    char* As = lds;
    char* Bs = lds + 16384;

    int row0 = blockIdx.x * 128;
    const uint16_t* b2 = W2;
    if (ROUTED) {
        if (row0 >= offs[NEXP]) return;
        int e = 0;
        while (row0 >= offs[e + 1]) ++e;
        b2 += (size_t)e * DIMD * HIDN;
    }
    int col0 = blockIdx.y * 128;

    int tid = threadIdx.x, lane = tid & 63;
    int wv = tid >> 6, wm = wv >> 1, wn = wv & 1;

    f32x4 acc[4][4] = {};

    for (int kt = 0; kt < K; kt += 64) {
        const uint16_t* bb = b2 + (size_t)(kt / kSplit) * expStride + (kt % kSplit);
        __syncthreads();
        stage128x64(A  + (size_t)row0 * lda + kt, lda, As, wv, lane);
        stage128x64(bb + (size_t)col0 * kSplit, kSplit, Bs, wv, lane);
        __syncthreads();

        #pragma unroll
        for (int s = 0; s < 2; ++s) {
            int cb = s * 64 + ((lane >> 4) << 4);
            s16x8 av[4];
            #pragma unroll
            for (int i = 0; i < 4; ++i)
                av[i] = *(const s16x8*)(As + swz(wm * 64 + i * 16 + (lane & 15), cb));
            #pragma unroll
            for (int j = 0; j < 4; ++j) {
                s16x8 bv = *(const s16x8*)(Bs + swz(wn * 64 + j * 16 + (lane & 15), cb));
                #pragma unroll
                for (int i = 0; i < 4; ++i)
                    acc[i][j] = __builtin_amdgcn_mfma_f32_16x16x32_bf16(av[i], bv, acc[i][j], 0, 0, 0);
            }
        }
    }

    #pragma unroll
    for (int i = 0; i < 4; ++i) {
        #pragma unroll
        for (int j = 0; j < 4; ++j) {
            #pragma unroll
            for (int rg = 0; rg < 4; ++rg) {
                int row = row0 + wm * 64 + i * 16 + ((lane >> 4) << 2) + rg;
                int col = col0 + wn * 64 + j * 16 + (lane & 15);
                float v = acc[i][j][rg];
                if (ROUTED) ((uint16_t*)Cout)[(size_t)row * DIMD + col] = f2bf(v);
                else        ((float*)Cout)[(size_t)row * DIMD + col] += v;
            }
        }
    }
}

// ---------------- launch ----------------

extern "C" void kernel_launch(void* const* d_in, const int* in_sizes, int n_in,
                              void* d_out, int out_size, void* d_ws, size_t ws_size,
                              hipStream_t stream) {
    const float* x   = (const float*)d_in[0];
    const float* rw  = (const float*)d_in[1];
    const float* eb  = (const float*)d_in[2];
    const float* w1  = (const float*)d_in[3];
    const float* w3  = (const float*)d_in[4];
    const float* w2  = (const float*)d_in[5];
    const float* sw1 = (const float*)d_in[6];
    const float* sw3 = (const float*)d_in[7];
    const float* sw2 = (const float*)d_in[8];
    float* out = (float*)d_out;

    const int EW = NEXP * HIDN * DIMD;   // 16,777,216 elements per routed weight
    const int SW = 2 * HIDN * DIMD;      //  4,194,304 elements per shared weight

    char* ws = (char*)d_ws;
    size_t off = 0;
    auto alloc = [&](size_t b) { char* p = ws + off; off = (off + b + 255) & ~(size_t)255; return p; };
    uint16_t* xb  = (uint16_t*)alloc((size_t)T_TOK * DIMD * 2);   // x in bf16
    uint16_t* Xg  = (uint16_t*)alloc((size_t)RMAX * DIMD * 2);    // gathered tokens
    uint16_t* Hg  = (uint16_t*)alloc((size_t)RMAX * HIDN * 2);    // hidden (reused for shared, ldh=4096)
    uint16_t* H2g = (uint16_t*)alloc((size_t)RMAX * DIMD * 2);    // routed expert outputs
    uint16_t* w1b = (uint16_t*)alloc((size_t)EW * 2);
    uint16_t* w3b = (uint16_t*)alloc((size_t)EW * 2);
    uint16_t* w2b = (uint16_t*)alloc((size_t)EW * 2);
    uint16_t* sw1b = (uint16_t*)alloc((size_t)SW * 2);
    uint16_t* sw3b = (uint16_t*)alloc((size_t)SW * 2);
    uint16_t* sw2b = (uint16_t*)alloc((size_t)SW * 2);
    int*   sel    = (int*)  alloc(T_TOK * 2 * 4);
    float* wgt    = (float*)alloc(T_TOK * 2 * 4);
    int*   row_of = (int*)  alloc(T_TOK * 2 * 4);
    int*   cnt    = (int*)  alloc(64);
    int*   fill   = (int*)  alloc(64);
    int*   offs   = (int*)  alloc(64);

    hipMemsetAsync(cnt, 0, 64, stream);
    hipMemsetAsync(fill, 0, 64, stream);
    hipMemsetAsync(Xg, 0, (size_t)RMAX * DIMD * 2, stream);      // zero pad rows
    hipMemsetAsync(out, 0, (size_t)out_size * sizeof(float), stream);

    // weight conversion f32 -> bf16 (one-shot, HBM-bound)
    cvt_w_kernel<<<2048, 256, 0, stream>>>(w1,  w1b,  EW / 4);
    cvt_w_kernel<<<2048, 256, 0, stream>>>(w3,  w3b,  EW / 4);
    cvt_w_kernel<<<2048, 256, 0, stream>>>(w2,  w2b,  EW / 4);
    cvt_w_kernel<<<1024, 256, 0, stream>>>(sw1, sw1b, SW / 4);
    cvt_w_kernel<<<1024, 256, 0, stream>>>(sw3, sw3b, SW / 4);
    cvt_w_kernel<<<1024, 256, 0, stream>>>(sw2, sw2b, SW / 4);

    cvt_x_kernel<<<4096, 256, 0, stream>>>(x, xb);
    router_kernel<<<T_TOK, 64, 0, stream>>>(x, rw, eb, sel, wgt);
    count_kernel<<<32, 256, 0, stream>>>(sel, cnt);
    offs_kernel<<<1, 1, 0, stream>>>(cnt, offs);
    assign_kernel<<<32, 256, 0, stream>>>(sel, offs, fill, row_of);
    gather_kernel<<<T_TOK * 2, 128, 0, stream>>>(xb, row_of, Xg);

    // routed experts: h = silu(Xg w1^T) * (Xg w3^T); H2g = h w2^T
    gemm13_kernel<1><<<dim3(RMAX / 128, HIDN / 128), 256, 0, stream>>>(Xg, w1b, w3b, Hg, HIDN, offs);
    gemm2_kernel<1><<<dim3(RMAX / 128, DIMD / 128), 256, 0, stream>>>(Hg, HIDN, w2b, (void*)H2g, offs,
                                                                      HIDN, HIDN, 0);
    combine_kernel<<<T_TOK, 128, 0, stream>>>(H2g, row_of, wgt, out);

    // shared experts folded into one GEMM pair: N-concat for GEMM1, K-concat for GEMM2
    gemm13_kernel<0><<<dim3(T_TOK / 128, (2 * HIDN) / 128), 256, 0, stream>>>(xb, sw1b, sw3b, Hg, 2 * HIDN, nullptr);
    gemm2_kernel<0><<<dim3(T_TOK / 128, DIMD / 128), 256, 0, stream>>>(Hg, 2 * HIDN, sw2b, (void*)out, nullptr,
                                                                       2 * HIDN, HIDN, (long long)DIMD * HIDN);
}